// Round 1
// baseline (757.131 us; speedup 1.0000x reference)
//
#include <hip/hip_runtime.h>
#include <cstdint>

// BloomEmbedding: 4 hash functions, table [4][1e6][32] f32, out [N][128] f32.
// Memory-bound: ~420 MB random 128B gathers + ~420 MB coalesced writes.

#define TABLE_SIZE 1000000u
#define SEED 42u

__device__ __forceinline__ uint32_t hash_id(uint32_t x) {
    x ^= x >> 16;
    x *= 0x7FEB352Du;
    x ^= x >> 15;
    x *= 0x846CA68Bu;
    x ^= x >> 16;
    return x % TABLE_SIZE;
}

// 32 threads per id; lane = h*8 + d4. Each thread moves one float4 (16 B).
// 8 lanes read one 128 B table row (coalesced); writes are 128 B/id contiguous.
__global__ void bloom_emb_kernel(const int* __restrict__ ids,
                                 const float4* __restrict__ tables,
                                 float4* __restrict__ out,
                                 int n) {
    int tid = blockIdx.x * blockDim.x + threadIdx.x;
    int gid  = tid >> 5;   // id index
    int lane = tid & 31;   // 0..31 within id
    if (gid >= n) return;

    int h  = lane >> 3;    // hash index 0..3
    int d4 = lane & 7;     // float4 index within 32-f32 sub-row

    uint32_t x = (uint32_t)ids[gid] + SEED + (uint32_t)h;
    uint32_t idx = hash_id(x);

    // tables: [4][TABLE_SIZE][8 x float4]
    const float4 v = tables[((size_t)h * TABLE_SIZE + idx) * 8 + (size_t)d4];
    out[(size_t)gid * 32 + (size_t)lane] = v;
}

extern "C" void kernel_launch(void* const* d_in, const int* in_sizes, int n_in,
                              void* d_out, int out_size, void* d_ws, size_t ws_size,
                              hipStream_t stream) {
    const int*   ids    = (const int*)d_in[0];
    const float* tables = (const float*)d_in[1];
    float*       out    = (float*)d_out;

    const int n = in_sizes[0];                 // 819200 ids
    const long long total_threads = (long long)n * 32;
    const int block = 256;
    const int grid = (int)((total_threads + block - 1) / block);

    bloom_emb_kernel<<<grid, block, 0, stream>>>(
        ids, (const float4*)tables, (float4*)out, n);
}